// Round 10
// baseline (249.291 us; speedup 1.0000x reference)
//
#include <hip/hip_runtime.h>

#define N_NODES 100000
#define N_EDGES 1600000
#define D_FEAT  48

#define BKT_SHIFT 9                                   // 512 nodes per coarse bucket
#define BKT_NODES (1 << BKT_SHIFT)
#define NBKT ((N_NODES + BKT_NODES - 1) / BKT_NODES)  // 196
#define EPB1 2048                                     // edges per phase-1 block
#define NB1  ((N_EDGES + EPB1 - 1) / EPB1)            // 782
#define P2_CAP 9216                                   // LDS-staged edges (avg 8163)
#define TILE_SHIFT 14                                 // src tile = src>>14 (0..6)
#define NTILE 8
#define KEYS (BKT_NODES * NTILE)                      // 4096

__device__ __forceinline__ unsigned short bf16_rn(float f) {
    unsigned u = __float_as_uint(f);
    unsigned r = (u + 0x7fffu + ((u >> 16) & 1u)) >> 16;
    return (unsigned short)r;
}
__device__ __forceinline__ float bf2f(unsigned short b) {
    return __uint_as_float(((unsigned)b) << 16);
}

// ---------- fused: x(f32)->xb(bf16)  +  coarse histogram ----------
__global__ void cvt_hist_kernel(const float* __restrict__ in,
                                unsigned short* __restrict__ outb,
                                const int* __restrict__ dst,
                                int* __restrict__ ccount) {
    __shared__ int cnt[NBKT];
    for (int i = threadIdx.x; i < NBKT; i += blockDim.x) cnt[i] = 0;
    __syncthreads();
    int tid = blockIdx.x * blockDim.x + threadIdx.x;
    int stride = gridDim.x * blockDim.x;
    const float4* in4 = (const float4*)in;
    ushort4* o4 = (ushort4*)outb;
    const int n4 = (N_NODES * D_FEAT) / 4;
    for (int i = tid; i < n4; i += stride) {
        float4 v = in4[i];
        ushort4 o;
        o.x = bf16_rn(v.x); o.y = bf16_rn(v.y);
        o.z = bf16_rn(v.z); o.w = bf16_rn(v.w);
        o4[i] = o;
    }
    for (int e = tid; e < N_EDGES; e += stride)
        atomicAdd(&cnt[dst[e] >> BKT_SHIFT], 1);
    __syncthreads();
    for (int i = threadIdx.x; i < NBKT; i += blockDim.x)
        if (cnt[i]) atomicAdd(&ccount[i], cnt[i]);
}

__global__ void scan196_kernel(const int* __restrict__ ccount,
                               int* __restrict__ bbase,
                               int* __restrict__ cursor,
                               int* __restrict__ row_ptr) {
    __shared__ int sdata[256];
    int t = threadIdx.x;
    int v = (t < NBKT) ? ccount[t] : 0;
    sdata[t] = v;
    __syncthreads();
    for (int off = 1; off < 256; off <<= 1) {
        int u = (t >= off) ? sdata[t - off] : 0;
        __syncthreads();
        sdata[t] += u;
        __syncthreads();
    }
    if (t < NBKT) { int ex = sdata[t] - v; bbase[t] = ex; cursor[t] = ex; }
    if (t == 0)   { bbase[NBKT] = N_EDGES; row_ptr[N_NODES] = N_EDGES; }
}

// coarse.x = dst_local(9b) | src<<9 ; coarse.y = w bits.
__global__ void p1_kernel(const float* __restrict__ w,
                          const int*   __restrict__ src,
                          const int*   __restrict__ dst,
                          int*         __restrict__ cursor,
                          uint2*       __restrict__ coarse) {
    __shared__ uint2 stage[EPB1];
    __shared__ unsigned char sbkt[EPB1];
    __shared__ int cnt[NBKT], base[NBKT];
    for (int i = threadIdx.x; i < NBKT; i += blockDim.x) cnt[i] = 0;
    __syncthreads();
    int e0 = blockIdx.x * EPB1;
    int n = N_EDGES - e0; if (n > EPB1) n = EPB1;
    for (int i = threadIdx.x; i < n; i += blockDim.x) {
        int e = e0 + i;
        int d = dst[e];
        int b = d >> BKT_SHIFT;
        atomicAdd(&cnt[b], 1);
        stage[i] = make_uint2((unsigned)(d & (BKT_NODES - 1)) | ((unsigned)src[e] << BKT_SHIFT),
                              (unsigned)__float_as_uint(w[e]));
        sbkt[i] = (unsigned char)b;
    }
    __syncthreads();
    for (int i = threadIdx.x; i < NBKT; i += blockDim.x) {
        int c = cnt[i];
        base[i] = c ? atomicAdd(&cursor[i], c) : 0;
        cnt[i] = 0;  // reuse as local cursor
    }
    __syncthreads();
    for (int i = threadIdx.x; i < n; i += blockDim.x) {
        int b = sbkt[i];
        int pos = base[b] + atomicAdd(&cnt[b], 1);
        coarse[pos] = stage[i];
    }
}

// Phase 2: one block per coarse bucket; key = dst_local*8 + src_tile.
// Thread t owns node (b<<9)+t -> writes row_ptr AND the 8 per-tile offsets.
__global__ __launch_bounds__(512) void p2_kernel(const uint2* __restrict__ coarse,
                                                 const int*   __restrict__ bbase,
                                                 int2*        __restrict__ recs,
                                                 int*         __restrict__ row_ptr,
                                                 int*         __restrict__ key_ptr) {
    __shared__ uint2 sedge[P2_CAP];     // 72 KB
    __shared__ int cnt[KEYS];           // 16 KB
    __shared__ int ssum[512];           // 2 KB
    int b = blockIdx.x, t = threadIdx.x;
    int lo = bbase[b], hi = bbase[b + 1];
    int m = hi - lo;
    int staged = (m < P2_CAP) ? m : P2_CAP;
    for (int i = t; i < staged; i += 512) sedge[i] = coarse[lo + i];
    for (int k = t; k < KEYS; k += 512) cnt[k] = 0;
    __syncthreads();
    for (int i = t; i < m; i += 512) {
        uint2 r = (i < staged) ? sedge[i] : coarse[lo + i];
        unsigned key = ((r.x & (BKT_NODES - 1)) << 3) | ((r.x >> BKT_SHIFT) >> TILE_SHIFT);
        atomicAdd(&cnt[key], 1);
    }
    __syncthreads();
    int base = t << 3;
    int local[NTILE];
    int s = 0;
#pragma unroll
    for (int j = 0; j < NTILE; ++j) { local[j] = s; s += cnt[base + j]; }
    ssum[t] = s;
    __syncthreads();
    for (int off = 1; off < 512; off <<= 1) {
        int u = (t >= off) ? ssum[t - off] : 0;
        __syncthreads();
        ssum[t] += u;
        __syncthreads();
    }
    int pre = lo + ssum[t] - s;          // global start of this node's edges
    int node = (b << BKT_SHIFT) + t;
    if (node < N_NODES) {
        row_ptr[node] = pre;
#pragma unroll
        for (int j = 0; j < NTILE; ++j) key_ptr[node * NTILE + j] = pre + local[j];
    }
#pragma unroll
    for (int j = 0; j < NTILE; ++j) cnt[base + j] = pre + local[j];
    __syncthreads();
    for (int i = t; i < m; i += 512) {
        uint2 r = (i < staged) ? sedge[i] : coarse[lo + i];
        unsigned src = r.x >> BKT_SHIFT;
        unsigned key = ((r.x & (BKT_NODES - 1)) << 3) | (src >> TILE_SHIFT);
        int pos = atomicAdd(&cnt[key], 1);
        recs[pos] = make_int2((int)src, (int)r.y);
    }
}

// ---------- SpMM gather: explicit src-tile phase loop ----------
__device__ __forceinline__ void acc4(float* a, ushort4 u, float w) {
    a[0] += w * bf2f(u.x);
    a[1] += w * bf2f(u.y);
    a[2] += w * bf2f(u.z);
    a[3] += w * bf2f(u.w);
}

template <bool OUT_BF16>
__global__ void spmm_gather_b_kernel(const unsigned short* __restrict__ xb,
                                     const int2* __restrict__ recs,
                                     const int*  __restrict__ row_ptr,
                                     const int*  __restrict__ key_ptr,
                                     void* __restrict__ outv) {
    int tid = blockIdx.x * blockDim.x + threadIdx.x;
    int n = tid >> 2;
    int l = tid & 3;
    bool active = (n < N_NODES);
    int nc = active ? n : (N_NODES - 1);
    int k[NTILE + 1];
    const int4* kp4 = reinterpret_cast<const int4*>(key_ptr) + (size_t)nc * 2;
    int4 ka = kp4[0], kb = kp4[1];
    k[0] = ka.x; k[1] = ka.y; k[2] = ka.z; k[3] = ka.w;
    k[4] = kb.x; k[5] = kb.y; k[6] = kb.z; k[7] = kb.w;
    k[8] = row_ptr[nc + 1];
    if (!active) {
#pragma unroll
        for (int j = 0; j <= NTILE; ++j) k[j] = 0;
    }
    float a0[4] = {0.f, 0.f, 0.f, 0.f};
    float a1[4] = {0.f, 0.f, 0.f, 0.f};
    float a2[4] = {0.f, 0.f, 0.f, 0.f};
    const ushort4* __restrict__ X = reinterpret_cast<const ushort4*>(xb);
    // Explicit tile loop: wave exec-mask forces all 16 nodes of this wave to
    // drain tile j before tile j+1 -> concurrent read set ~ one 1.57 MB tile.
#pragma unroll
    for (int j = 0; j < NTILE; ++j) {
        int e = k[j], end = k[j + 1];
        for (; e + 1 < end; e += 2) {
            int2 r0 = recs[e], r1 = recs[e + 1];
            const ushort4* x0 = X + (size_t)r0.x * (D_FEAT / 4);
            const ushort4* x1 = X + (size_t)r1.x * (D_FEAT / 4);
            ushort4 u00 = x0[l], u01 = x0[4 + l], u02 = x0[8 + l];
            ushort4 u10 = x1[l], u11 = x1[4 + l], u12 = x1[8 + l];
            float w0 = __int_as_float(r0.y), w1 = __int_as_float(r1.y);
            acc4(a0, u00, w0); acc4(a1, u01, w0); acc4(a2, u02, w0);
            acc4(a0, u10, w1); acc4(a1, u11, w1); acc4(a2, u12, w1);
        }
        if (e < end) {
            int2 r = recs[e];
            float we = __int_as_float(r.y);
            const ushort4* xr = X + (size_t)r.x * (D_FEAT / 4);
            acc4(a0, xr[l], we); acc4(a1, xr[4 + l], we); acc4(a2, xr[8 + l], we);
        }
    }
    if (!active) return;
    if (OUT_BF16) {
        ushort4* orow = reinterpret_cast<ushort4*>((unsigned short*)outv + (size_t)n * D_FEAT);
        ushort4 o0, o1, o2;
        o0.x = bf16_rn(a0[0]); o0.y = bf16_rn(a0[1]); o0.z = bf16_rn(a0[2]); o0.w = bf16_rn(a0[3]);
        o1.x = bf16_rn(a1[0]); o1.y = bf16_rn(a1[1]); o1.z = bf16_rn(a1[2]); o1.w = bf16_rn(a1[3]);
        o2.x = bf16_rn(a2[0]); o2.y = bf16_rn(a2[1]); o2.z = bf16_rn(a2[2]); o2.w = bf16_rn(a2[3]);
        orow[l] = o0; orow[4 + l] = o1; orow[8 + l] = o2;
    } else {
        float4* orow = reinterpret_cast<float4*>((float*)outv + (size_t)n * D_FEAT);
        orow[l]     = make_float4(a0[0], a0[1], a0[2], a0[3]);
        orow[4 + l] = make_float4(a1[0], a1[1], a1[2], a1[3]);
        orow[8 + l] = make_float4(a2[0], a2[1], a2[2], a2[3]);
    }
}

extern "C" void kernel_launch(void* const* d_in, const int* in_sizes, int n_in,
                              void* d_out, int out_size, void* d_ws, size_t ws_size,
                              hipStream_t stream) {
    const float* x    = (const float*)d_in[0];
    const float* ew   = (const float*)d_in[1];
    const int*   esrc = (const int*)d_in[2];
    const int*   edst = (const int*)d_in[3];
    float* out = (float*)d_out;

    // Workspace layout. tmpb shares its slot with coarse (p2 consumes coarse
    // before spmm pass 1 writes tmpb).
    char* ws = (char*)d_ws;
    unsigned short* xb = (unsigned short*)ws;                 // 9.6 MB
    ws += (((size_t)N_NODES * D_FEAT * sizeof(unsigned short)) + 15) & ~15ull;
    unsigned short* tmpb = (unsigned short*)ws;
    uint2* coarse = (uint2*)ws;
    ws += (size_t)N_EDGES * sizeof(uint2);                    // 12.8 MB
    int2* recs = (int2*)ws;
    ws += (size_t)N_EDGES * sizeof(int2);                     // 12.8 MB
    int* row_ptr = (int*)ws;
    ws += ((size_t)(N_NODES + 1) * sizeof(int) + 15) & ~15ull;
    int* key_ptr = (int*)ws;                                  // 3.2 MB
    ws += ((size_t)N_NODES * NTILE * sizeof(int) + 15) & ~15ull;
    int* ccount = (int*)ws;
    ws += ((size_t)NBKT * sizeof(int) + 15) & ~15ull;
    int* bbase = (int*)ws;
    ws += ((size_t)(NBKT + 1) * sizeof(int) + 15) & ~15ull;
    int* cursor = (int*)ws;

    dim3 blk(256);
    dim3 grid_nodes(((size_t)N_NODES * 4 + 255) / 256);

    // CSR build + bf16 conversion
    hipMemsetAsync(ccount, 0, NBKT * sizeof(int), stream);
    cvt_hist_kernel<<<1024, blk, 0, stream>>>(x, xb, edst, ccount);
    scan196_kernel<<<1, blk, 0, stream>>>(ccount, bbase, cursor, row_ptr);
    p1_kernel<<<NB1, blk, 0, stream>>>(ew, esrc, edst, cursor, coarse);
    p2_kernel<<<NBKT, dim3(512), 0, stream>>>(coarse, bbase, recs, row_ptr, key_ptr);

    // Pass 1: tmpb = bf16(A @ xb) ; Pass 2: out = A @ tmpb (f32 out)
    spmm_gather_b_kernel<true><<<grid_nodes, blk, 0, stream>>>(xb, recs, row_ptr, key_ptr, tmpb);
    spmm_gather_b_kernel<false><<<grid_nodes, blk, 0, stream>>>(tmpb, recs, row_ptr, key_ptr, out);
}